// Round 7
// baseline (6262.321 us; speedup 1.0000x reference)
//
#include <hip/hip_runtime.h>

#define HW_ (512 * 512)
#define B_ 8
#define H_ 512
#define W_ 512
#define K_ 32
#define CH_ 16
#define CHPIX_ (HW_ / CH_)  // 16384 pixels per chunk

// ---------------- compact phase A: per-chunk valid count ----------------
__global__ void k_count(const float* __restrict__ seg, int* __restrict__ chunkCnt) {
  const int blk = blockIdx.x;  // b*CH_ + c
  const int t = threadIdx.x;
  const float4* __restrict__ s4 = (const float4*)(seg + (size_t)blk * CHPIX_) + (size_t)t * 16;
  int cnt = 0;
#pragma unroll
  for (int j = 0; j < 16; ++j) {
    float4 v = s4[j];
    cnt += (v.x >= 0.9f) + (v.y >= 0.9f) + (v.z >= 0.9f) + (v.w >= 0.9f);
  }
  __shared__ int red[256];
  red[t] = cnt;
  __syncthreads();
  for (int off = 128; off > 0; off >>= 1) {
    if (t < off) red[t] += red[t + off];
    __syncthreads();
  }
  if (t == 0) chunkCnt[blk] = red[0];
}

// ---------------- compact phase B: per-batch chunk base offsets ----------------
__global__ void k_scan(const int* __restrict__ chunkCnt, int* __restrict__ chunkBase,
                       int* __restrict__ nvalid, int cap) {
  const int t = threadIdx.x;  // b*CH_ + c
  if (t < B_ * CH_) {
    const int b = t / CH_, c = t % CH_;
    int base = 0;
    for (int q = 0; q < c; ++q) base += chunkCnt[b * CH_ + q];
    chunkBase[t] = base;
    if (c == CH_ - 1) nvalid[b] = min(base + chunkCnt[t], cap);
  }
}

// ---------------- compact phase C: ordered compaction + gather + lanes memset ----------------
__global__ void k_fill(const float* __restrict__ seg, const float* __restrict__ emb,
                       const int* __restrict__ chunkBase, unsigned char* __restrict__ lanes,
                       int* __restrict__ idxC, float* __restrict__ embC, int cap) {
  const int blk = blockIdx.x;  // b*CH_ + c
  const int b = blk / CH_;
  const int t = threadIdx.x;
  const size_t pixbase = (size_t)blk * CHPIX_ + (size_t)t * 64;
  const float4* __restrict__ s4 = (const float4*)(seg + pixbase);

  int cnt = 0;
#pragma unroll
  for (int j = 0; j < 16; ++j) {
    float4 v = s4[j];
    cnt += (v.x >= 0.9f) + (v.y >= 0.9f) + (v.z >= 0.9f) + (v.w >= 0.9f);
  }
  __shared__ int pre[256];
  pre[t] = cnt;
  __syncthreads();
  for (int off = 1; off < 256; off <<= 1) {
    int mine = pre[t];
    int add = (t >= off) ? pre[t - off] : 0;
    __syncthreads();
    pre[t] = mine + add;
    __syncthreads();
  }
  int w = chunkBase[blk] + pre[t] - cnt;

  uint4 z = {0u, 0u, 0u, 0u};
  uint4* lz = (uint4*)(lanes + pixbase);
  lz[0] = z; lz[1] = z; lz[2] = z; lz[3] = z;

  const float* __restrict__ eb = emb + (size_t)b * 8 * HW_;
  const int pixInB = (int)(pixbase - (size_t)b * HW_);
  for (int j = 0; j < 16; ++j) {
    float4 v = s4[j];
    float sv[4] = {v.x, v.y, v.z, v.w};
#pragma unroll
    for (int q = 0; q < 4; ++q) {
      if (sv[q] >= 0.9f && w < cap) {
        const int p = pixInB + j * 4 + q;
        idxC[(size_t)b * cap + w] = p;
        float* dst = embC + ((size_t)b * cap + w) * 8;
#pragma unroll
        for (int dd = 0; dd < 8; ++dd) dst[dd] = eb[(size_t)dd * HW_ + p];
        ++w;
      }
    }
  }
}

// ---------------- sequential clustering: dual-batch per wave ----------------
// 4 blocks x 1 wave. Lanes 0-31: batch 2*blk centers; lanes 32-63: batch 2*blk+1.
// Phase = 16 pixels per batch. ONE global_load_lds per phase stages both batches
// (per-lane global source picks the batch; LDS dest linear: A = first 512B, B = next).
// ONE ds_read_b128 per phase -> td. Per pair-step: 16 v_readlane broadcasts,
// shared 4-level v_min_u32_dpp reduce (A keys in lanes 0-31, B in 32-63).

#define PHPX_ 16  // pixels per batch per phase

__device__ __forceinline__ void stage16(const float* g, float* l) {
  __builtin_amdgcn_global_load_lds(
      (const __attribute__((address_space(1))) void*)g,
      (__attribute__((address_space(3))) void*)l, 16, 0, 0);
}

#define RLF(V, L) __uint_as_float((unsigned)__builtin_amdgcn_readlane(__float_as_int(V), (L)))
#define RLU(V, L) ((unsigned)__builtin_amdgcn_readlane((int)(V), (L)))

#define PSTEP(J)                                                                   \
  do {                                                                             \
    const float eA0 = RLF(td.x, 2 * (J)), eA1 = RLF(td.y, 2 * (J));                \
    const float eA2 = RLF(td.z, 2 * (J)), eA3 = RLF(td.w, 2 * (J));                \
    const float eA4 = RLF(td.x, 2 * (J) + 1), eA5 = RLF(td.y, 2 * (J) + 1);        \
    const float eA6 = RLF(td.z, 2 * (J) + 1), eA7 = RLF(td.w, 2 * (J) + 1);        \
    const float eB0 = RLF(td.x, 32 + 2 * (J)), eB1 = RLF(td.y, 32 + 2 * (J));      \
    const float eB2 = RLF(td.z, 32 + 2 * (J)), eB3 = RLF(td.w, 32 + 2 * (J));      \
    const float eB4 = RLF(td.x, 33 + 2 * (J)), eB5 = RLF(td.y, 33 + 2 * (J));      \
    const float eB6 = RLF(td.z, 33 + 2 * (J)), eB7 = RLF(td.w, 33 + 2 * (J));      \
    float t0 = hi ? (C0 - eB0) : (C0 - eA0);                                       \
    float t1 = hi ? (C1 - eB1) : (C1 - eA1);                                       \
    float t2 = hi ? (C2 - eB2) : (C2 - eA2);                                       \
    float t3 = hi ? (C3 - eB3) : (C3 - eA3);                                       \
    float t4 = hi ? (C4 - eB4) : (C4 - eA4);                                       \
    float t5 = hi ? (C5 - eB5) : (C5 - eA5);                                       \
    float t6 = hi ? (C6 - eB6) : (C6 - eA6);                                       \
    float t7 = hi ? (C7 - eB7) : (C7 - eA7);                                       \
    float a0 = t0 * t0 + t1 * t1;                                                  \
    float a1 = t2 * t2 + t3 * t3;                                                  \
    float a2 = t4 * t4 + t5 * t5;                                                  \
    float a3 = t6 * t6 + t7 * t7;                                                  \
    float dsq = (a0 + a1) + (a2 + a3);                                             \
    unsigned db = __float_as_uint(dsq);                                            \
    unsigned dbm = db > emptyBits ? db : emptyBits; /* empty center -> inf */      \
    unsigned mn = (dbm & 0xFFFFFFE0u) | (unsigned)cl;                              \
    asm volatile(                                                                  \
        "s_nop 1\n\t"                                                              \
        "v_min_u32_dpp %0, %0, %0 quad_perm:[1,0,3,2] row_mask:0xf bank_mask:0xf\n\t" \
        "s_nop 1\n\t"                                                              \
        "v_min_u32_dpp %0, %0, %0 quad_perm:[2,3,0,1] row_mask:0xf bank_mask:0xf\n\t" \
        "s_nop 1\n\t"                                                              \
        "v_min_u32_dpp %0, %0, %0 row_half_mirror row_mask:0xf bank_mask:0xf\n\t"  \
        "s_nop 1\n\t"                                                              \
        "v_min_u32_dpp %0, %0, %0 row_mirror row_mask:0xf bank_mask:0xf\n\t"       \
        "s_nop 1"                                                                  \
        : "+v"(mn));                                                               \
    unsigned q0 = RLU(mn, 0), q1 = RLU(mn, 16);                                    \
    unsigned q2 = RLU(mn, 32), q3 = RLU(mn, 48);                                   \
    unsigned mvA = q0 < q1 ? q0 : q1; /* uniform -> SALU */                        \
    unsigned mvB = q2 < q3 ? q2 : q3;                                              \
    bool joinA = mvA < 0x41100000u; /* dsq < 9.0 <=> sqrt(dsq) < 3 */              \
    bool joinB = mvB < 0x41100000u;                                                \
    int cidA = joinA ? (int)(mvA & 31u) : (nactA < 31 ? nactA : 31);               \
    int cidB = joinB ? (int)(mvB & 31u) : (nactB < 31 ? nactB : 31);               \
    nactA += joinA ? 0 : 1;                                                        \
    nactB += joinB ? 0 : 1;                                                        \
    bool own = (cl == (hi ? cidB : cidA));                                         \
    bool join_my = hi ? joinB : joinA;                                             \
    float wj = join_my ? inv : 1.0f;                                               \
    float w = own ? wj : 0.0f;                                                     \
    C0 = __builtin_fmaf(t0, -w, C0);                                               \
    C1 = __builtin_fmaf(t1, -w, C1);                                               \
    C2 = __builtin_fmaf(t2, -w, C2);                                               \
    C3 = __builtin_fmaf(t3, -w, C3);                                               \
    C4 = __builtin_fmaf(t4, -w, C4);                                               \
    C5 = __builtin_fmaf(t5, -w, C5);                                               \
    C6 = __builtin_fmaf(t6, -w, C6);                                               \
    C7 = __builtin_fmaf(t7, -w, C7);                                               \
    cnt += own ? 1.0f : 0.0f;                                                      \
    inv = __builtin_amdgcn_rcpf(cnt + 1.0f); /* off-chain: used next step */       \
    emptyBits = own ? 0u : emptyBits;                                              \
    pkA |= (unsigned long long)(unsigned)(cidA + 1) << (((J) & 7) * 8);            \
    pkB |= (unsigned long long)(unsigned)(cidB + 1) << (((J) & 7) * 8);            \
    if (((J) & 7) == 7) {                                                          \
      if (lane == 0) *(unsigned long long*)(cpA + ((J) & ~7)) = pkA;               \
      if (lane == 32) *(unsigned long long*)(cpB + ((J) & ~7)) = pkB;              \
      pkA = 0ULL;                                                                  \
      pkB = 0ULL;                                                                  \
    }                                                                              \
  } while (0)

__global__ __launch_bounds__(64, 1) void k_cluster(const float* __restrict__ embC,
                                                   const int* __restrict__ nvalid,
                                                   unsigned char* __restrict__ cidArr,
                                                   int cap) {
  __shared__ float lds[512];  // 2 phases x 256 floats (1KB each: A 512B | B 512B)
  const int blk = blockIdx.x;  // 0..3
  const int lane = threadIdx.x;
  const bool hi = lane >= 32;
  const int cl = lane & 31;
  const int bA = 2 * blk, bB = 2 * blk + 1;
  const int nA = nvalid[bA], nB = nvalid[bB];
  const int nMax = nA > nB ? nA : nB;
  if (nMax <= 0) return;
  const int nPh = (nMax + PHPX_ - 1) / PHPX_;

  // per-lane staging source: lanes 0-31 read batch A's tile-half, 32-63 batch B's
  const float* gsrc = embC + (size_t)(hi ? bB : bA) * cap * 8 + (size_t)cl * 4;
  unsigned char* cA = cidArr + (size_t)bA * HW_;
  unsigned char* cB = cidArr + (size_t)bB * HW_;

  float C0 = 0.f, C1 = 0.f, C2 = 0.f, C3 = 0.f, C4 = 0.f, C5 = 0.f, C6 = 0.f, C7 = 0.f;
  float cnt = 0.f, inv = 1.0f;
  unsigned emptyBits = 0x7F800000u;
  int nactA = 0, nactB = 0;
  unsigned long long pkA = 0ULL, pkB = 0ULL;

  // prologue: stage phase 0, wait, pull my 16B into registers
  stage16(gsrc, lds);
  asm volatile("s_waitcnt vmcnt(0)" ::: "memory");
  __builtin_amdgcn_sched_barrier(0);
  float4 td = ((const float4*)lds)[lane];

  for (int ph = 0; ph < nPh; ++ph) {
    unsigned char* cpA = cA + ph * PHPX_;
    unsigned char* cpB = cB + ph * PHPX_;
    if (ph + 1 < nPh)  // stage next phase (16 px per batch = 128 floats each)
      stage16(gsrc + (size_t)(ph + 1) * 128, lds + ((ph + 1) & 1) * 256);

    PSTEP(0);  PSTEP(1);  PSTEP(2);  PSTEP(3);
    PSTEP(4);  PSTEP(5);  PSTEP(6);  PSTEP(7);
    PSTEP(8);  PSTEP(9);  PSTEP(10); PSTEP(11);
    PSTEP(12); PSTEP(13); PSTEP(14); PSTEP(15);

    if (ph + 1 < nPh) {
      // outstanding VMEM: stage(ph+1) + 4 pack-stores issued after it;
      // in-order retirement => vmcnt(4) <=> stage arrived.
      asm volatile("s_waitcnt vmcnt(4)" ::: "memory");
      __builtin_amdgcn_sched_barrier(0);
      td = ((const float4*)(lds + ((ph + 1) & 1) * 256))[lane];
    }
  }
}

// ---------------- scatter cid bytes to the per-pixel lane map ----------------
__global__ void k_scatter(const unsigned char* __restrict__ cidArr,
                          const int* __restrict__ idxC, const int* __restrict__ nvalid,
                          unsigned char* __restrict__ lanes, int cap) {
  const int b = blockIdx.y;
  const int n = nvalid[b];
  for (int j = blockIdx.x * blockDim.x + threadIdx.x; j < n; j += gridDim.x * blockDim.x) {
    lanes[(size_t)b * HW_ + idxC[(size_t)b * cap + j]] = cidArr[(size_t)b * HW_ + j];
  }
}

// ---------------- per-(b,h) segment sums over 33 lane bins ----------------
__global__ void k_rowsum(const unsigned char* __restrict__ lanes,
                         const float* __restrict__ offp, const float* __restrict__ zp,
                         float* __restrict__ cnt, float* __restrict__ sx,
                         float* __restrict__ sz) {
  const int bh = blockIdx.x;
  const int b = bh >> 9, h = bh & 511;
  __shared__ float sc[33], sxx[33], szz[33];
  const int t = threadIdx.x;
  if (t < 33) { sc[t] = 0.f; sxx[t] = 0.f; szz[t] = 0.f; }
  __syncthreads();
  const size_t base = (size_t)bh * W_;
  for (int x = t; x < W_; x += 256) {
    int ln = lanes[base + x];
    float o = offp[base + x];
    float sig = 1.0f / (1.0f + expf(-o));
    float xa = (float)x + sig;
    float zv = zp[base + x];
    atomicAdd(&sc[ln], 1.0f);
    atomicAdd(&sxx[ln], xa);
    atomicAdd(&szz[ln], zv);
  }
  __syncthreads();
  if (t >= 1 && t < 33) {
    size_t o = ((size_t)b * K_ + (t - 1)) * H_ + h;
    cnt[o] = sc[t]; sx[o] = sxx[t]; sz[o] = szz[t];
  }
}

// ---------------- validity + point assembly ----------------
__global__ void k_final(const float* __restrict__ cnt, const float* __restrict__ sx,
                        const float* __restrict__ sz, float* __restrict__ out) {
  const int bk = blockIdx.x;
  const int b = bk >> 5, k = bk & 31;
  const int h = threadIdx.x;
  const size_t o = (size_t)bk * H_ + h;
  float c = cnt[o];
  float sc_ = c, sn = (c > 0.f) ? 1.f : 0.f;
#pragma unroll
  for (int off = 32; off >= 1; off >>= 1) {
    sc_ += __shfl_down(sc_, off);
    sn += __shfl_down(sn, off);
  }
  __shared__ float rs[8], rn[8], tot[2];
  const int wid = h >> 6, lid = h & 63;
  if (lid == 0) { rs[wid] = sc_; rn[wid] = sn; }
  __syncthreads();
  if (h == 0) {
    float a = 0, bb = 0;
#pragma unroll
    for (int q = 0; q < 8; ++q) { a += rs[q]; bb += rn[q]; }
    tot[0] = a; tot[1] = bb;
  }
  __syncthreads();
  float size = tot[0], nrows = tot[1];
  bool valid = (c > 0.f) && (size >= 50.f) && (nrows >= 2.f);
  float mx = sx[o] / fmaxf(c, 1.f);
  float mz = sz[o] / fmaxf(c, 1.f);
  float xw = (512.0f - ((float)h + 0.5f)) * 0.2f;
  float yw = -(mx - 256.0f) * 0.2f;
  out[((size_t)(b * 3 + 0) * K_ + k) * H_ + h] = valid ? xw : 0.f;
  out[((size_t)(b * 3 + 1) * K_ + k) * H_ + h] = valid ? yw : 0.f;
  out[((size_t)(b * 3 + 2) * K_ + k) * H_ + h] = valid ? mz : 0.f;
  out[(size_t)B_ * 3 * K_ * H_ + (size_t)bk * H_ + h] = valid ? 1.f : 0.f;
}

extern "C" void kernel_launch(void* const* d_in, const int* in_sizes, int n_in,
                              void* d_out, int out_size, void* d_ws, size_t ws_size,
                              hipStream_t stream) {
  const float* seg  = (const float*)d_in[0];
  const float* emb  = (const float*)d_in[1];
  const float* offp = (const float*)d_in[2];
  const float* zp   = (const float*)d_in[3];
  float* out = (float*)d_out;
  char* ws = (char*)d_ws;

  const size_t lanesOff = 0;
  const size_t cntOff   = (size_t)B_ * HW_;
  const size_t sxOff    = cntOff + (size_t)B_ * K_ * H_ * 4;
  const size_t szOff    = sxOff  + (size_t)B_ * K_ * H_ * 4;
  const size_t nvOff    = szOff  + (size_t)B_ * K_ * H_ * 4;
  const size_t ccOff    = nvOff + 256;
  const size_t cbOff    = ccOff + 1024;
  const size_t cidOff   = cbOff + 1024;                      // u8 [B][HW_] = 2 MiB
  const size_t idxOff   = cidOff + (size_t)B_ * HW_;
  size_t avail = (ws_size > idxOff + 8192) ? (ws_size - idxOff - 8192) : 0;  // staging slack
  long long capLL = (long long)(avail / ((size_t)B_ * 36));  // 4B idx + 32B emb per entry
  if (capLL > (long long)HW_) capLL = HW_;
  if (capLL < 2) capLL = 2;
  capLL &= ~1LL;  // keep per-batch embC base 64B-aligned
  const int cap = (int)capLL;
  const size_t embOff = idxOff + (size_t)B_ * cap * 4;

  unsigned char* lanes = (unsigned char*)(ws + lanesOff);
  float* cnt = (float*)(ws + cntOff);
  float* sx  = (float*)(ws + sxOff);
  float* sz  = (float*)(ws + szOff);
  int* nvalid = (int*)(ws + nvOff);
  int* chunkCnt  = (int*)(ws + ccOff);
  int* chunkBase = (int*)(ws + cbOff);
  unsigned char* cidArr = (unsigned char*)(ws + cidOff);
  int* idxC   = (int*)(ws + idxOff);
  float* embC = (float*)(ws + embOff);

  k_count<<<B_ * CH_, 256, 0, stream>>>(seg, chunkCnt);
  k_scan<<<1, 128, 0, stream>>>(chunkCnt, chunkBase, nvalid, cap);
  k_fill<<<B_ * CH_, 256, 0, stream>>>(seg, emb, chunkBase, lanes, idxC, embC, cap);
  k_cluster<<<B_ / 2, 64, 0, stream>>>(embC, nvalid, cidArr, cap);
  k_scatter<<<dim3(64, B_), 256, 0, stream>>>(cidArr, idxC, nvalid, lanes, cap);
  k_rowsum<<<B_ * H_, 256, 0, stream>>>(lanes, offp, zp, cnt, sx, sz);
  k_final<<<B_ * K_, H_, 0, stream>>>(cnt, sx, sz, out);
}

// Round 8
// 3971.055 us; speedup vs baseline: 1.5770x; 1.5770x over previous
//
#include <hip/hip_runtime.h>

#define HW_ (512 * 512)
#define B_ 8
#define H_ 512
#define W_ 512
#define K_ 32
#define CH_ 16
#define CHPIX_ (HW_ / CH_)  // 16384 pixels per chunk

// ---------------- compact phase A: per-chunk valid count ----------------
__global__ void k_count(const float* __restrict__ seg, int* __restrict__ chunkCnt) {
  const int blk = blockIdx.x;  // b*CH_ + c
  const int t = threadIdx.x;
  const float4* __restrict__ s4 = (const float4*)(seg + (size_t)blk * CHPIX_) + (size_t)t * 16;
  int cnt = 0;
#pragma unroll
  for (int j = 0; j < 16; ++j) {
    float4 v = s4[j];
    cnt += (v.x >= 0.9f) + (v.y >= 0.9f) + (v.z >= 0.9f) + (v.w >= 0.9f);
  }
  __shared__ int red[256];
  red[t] = cnt;
  __syncthreads();
  for (int off = 128; off > 0; off >>= 1) {
    if (t < off) red[t] += red[t + off];
    __syncthreads();
  }
  if (t == 0) chunkCnt[blk] = red[0];
}

// ---------------- compact phase B: per-batch chunk base offsets ----------------
__global__ void k_scan(const int* __restrict__ chunkCnt, int* __restrict__ chunkBase,
                       int* __restrict__ nvalid, int cap) {
  const int t = threadIdx.x;  // b*CH_ + c
  if (t < B_ * CH_) {
    const int b = t / CH_, c = t % CH_;
    int base = 0;
    for (int q = 0; q < c; ++q) base += chunkCnt[b * CH_ + q];
    chunkBase[t] = base;
    if (c == CH_ - 1) nvalid[b] = min(base + chunkCnt[t], cap);
  }
}

// ---------------- compact phase C: ordered compaction + gather + lanes memset ----------------
__global__ void k_fill(const float* __restrict__ seg, const float* __restrict__ emb,
                       const int* __restrict__ chunkBase, unsigned char* __restrict__ lanes,
                       int* __restrict__ idxC, float* __restrict__ embC, int cap) {
  const int blk = blockIdx.x;  // b*CH_ + c
  const int b = blk / CH_;
  const int t = threadIdx.x;
  const size_t pixbase = (size_t)blk * CHPIX_ + (size_t)t * 64;
  const float4* __restrict__ s4 = (const float4*)(seg + pixbase);

  int cnt = 0;
#pragma unroll
  for (int j = 0; j < 16; ++j) {
    float4 v = s4[j];
    cnt += (v.x >= 0.9f) + (v.y >= 0.9f) + (v.z >= 0.9f) + (v.w >= 0.9f);
  }
  __shared__ int pre[256];
  pre[t] = cnt;
  __syncthreads();
  for (int off = 1; off < 256; off <<= 1) {
    int mine = pre[t];
    int add = (t >= off) ? pre[t - off] : 0;
    __syncthreads();
    pre[t] = mine + add;
    __syncthreads();
  }
  int w = chunkBase[blk] + pre[t] - cnt;

  uint4 z = {0u, 0u, 0u, 0u};
  uint4* lz = (uint4*)(lanes + pixbase);
  lz[0] = z; lz[1] = z; lz[2] = z; lz[3] = z;

  const float* __restrict__ eb = emb + (size_t)b * 8 * HW_;
  const int pixInB = (int)(pixbase - (size_t)b * HW_);
  for (int j = 0; j < 16; ++j) {
    float4 v = s4[j];
    float sv[4] = {v.x, v.y, v.z, v.w};
#pragma unroll
    for (int q = 0; q < 4; ++q) {
      if (sv[q] >= 0.9f && w < cap) {
        const int p = pixInB + j * 4 + q;
        idxC[(size_t)b * cap + w] = p;
        float* dst = embC + ((size_t)b * cap + w) * 8;
#pragma unroll
        for (int dd = 0; dd < 8; ++dd) dst[dd] = eb[(size_t)dd * HW_ + p];
        ++w;
      }
    }
  }
}

// ---------------- sequential clustering: SMEM e-delivery, pure-VGPR chain ----------------
// 8 blocks x 1 wave, one batch each. Centers on lanes 0-31 (32-63 mirror).
// The pixel stream is wave-uniform -> embeddings are loaded with SCALAR loads:
// 2 x s_load_dwordx16 per 4-pixel group (128B), double-buffered in SGPR slots.
// SMEM+SALU issue hides under the VALU shadow; no LDS, no readlane broadcasts,
// no vector loads in the loop at all (only the per-8px pack store).

typedef unsigned u32x16 __attribute__((ext_vector_type(16)));

#define RLU(V, L) ((unsigned)__builtin_amdgcn_readlane((int)(V), (L)))

// issue one 4-pixel group (two x16 scalar loads) into slot (SA,SB)
#define SLOAD(SA, SB, OFF)                                            \
  asm volatile("s_load_dwordx16 %0, %2, %3\n\t"                       \
               "s_load_dwordx16 %1, %2, %4"                           \
               : "=s"(SA), "=s"(SB)                                   \
               : "s"(src), "s"((OFF)), "s"((OFF) + 64u));

// wait for the slot's loads; tie the slots through the asm so no use can hoist
#define SWAIT(SA, SB) \
  asm volatile("s_waitcnt lgkmcnt(0)" : "+s"(SA), "+s"(SB));

#define STEPS(J, SV, BI)                                                              \
  do {                                                                               \
    const float e0 = __uint_as_float((SV)[(BI) + 0]);                                \
    const float e1 = __uint_as_float((SV)[(BI) + 1]);                                \
    const float e2 = __uint_as_float((SV)[(BI) + 2]);                                \
    const float e3 = __uint_as_float((SV)[(BI) + 3]);                                \
    const float e4 = __uint_as_float((SV)[(BI) + 4]);                                \
    const float e5 = __uint_as_float((SV)[(BI) + 5]);                                \
    const float e6 = __uint_as_float((SV)[(BI) + 6]);                                \
    const float e7 = __uint_as_float((SV)[(BI) + 7]);                                \
    float t0 = e0 - C0, t1 = e1 - C1, t2 = e2 - C2, t3 = e3 - C3;                    \
    float t4 = e4 - C4, t5 = e5 - C5, t6 = e6 - C6, t7 = e7 - C7;                    \
    float m0 = t0 * t0; m0 = __builtin_fmaf(t1, t1, m0);                             \
    float m1 = t2 * t2; m1 = __builtin_fmaf(t3, t3, m1);                             \
    float m2 = t4 * t4; m2 = __builtin_fmaf(t5, t5, m2);                             \
    float m3 = t6 * t6; m3 = __builtin_fmaf(t7, t7, m3);                             \
    float dsq = (m0 + m1) + (m2 + m3);                                               \
    unsigned db = __float_as_uint(dsq);                                              \
    unsigned dbm = db > emptyBits ? db : emptyBits; /* empty center -> inf */        \
    unsigned mn = (dbm & 0xFFFFFFE0u) | (unsigned)cl; /* key = dsq-trunc | cl */     \
    unsigned mr;                                                                     \
    mr = (unsigned)__builtin_amdgcn_update_dpp(0, (int)mn, 0xB1, 0xF, 0xF, true);    \
    mn = mn < mr ? mn : mr;                                                          \
    mr = (unsigned)__builtin_amdgcn_update_dpp(0, (int)mn, 0x4E, 0xF, 0xF, true);    \
    mn = mn < mr ? mn : mr;                                                          \
    mr = (unsigned)__builtin_amdgcn_update_dpp(0, (int)mn, 0x141, 0xF, 0xF, true);   \
    mn = mn < mr ? mn : mr;                                                          \
    mr = (unsigned)__builtin_amdgcn_update_dpp(0, (int)mn, 0x140, 0xF, 0xF, true);   \
    mn = mn < mr ? mn : mr;                                                          \
    unsigned q0 = RLU(mn, 0), q1 = RLU(mn, 16);                                      \
    unsigned mv = q0 < q1 ? q0 : q1; /* uniform -> SALU */                           \
    bool join = mv < 0x41100000u;    /* dsq < 9.0 <=> sqrt(dsq) < 3, exact */        \
    int cid = join ? (int)(mv & 31u) : (nact < 31 ? nact : 31);                      \
    nact += join ? 0 : 1;                                                            \
    bool own = (cl == cid);                                                          \
    float wj = join ? inv : 1.0f;                                                    \
    float w = own ? wj : 0.0f;                                                       \
    C0 = __builtin_fmaf(t0, w, C0); /* t = e-C: C += w*(e-C) */                      \
    C1 = __builtin_fmaf(t1, w, C1);                                                  \
    C2 = __builtin_fmaf(t2, w, C2);                                                  \
    C3 = __builtin_fmaf(t3, w, C3);                                                  \
    C4 = __builtin_fmaf(t4, w, C4);                                                  \
    C5 = __builtin_fmaf(t5, w, C5);                                                  \
    C6 = __builtin_fmaf(t6, w, C6);                                                  \
    C7 = __builtin_fmaf(t7, w, C7);                                                  \
    cnt += own ? 1.0f : 0.0f;                                                        \
    inv = __builtin_amdgcn_rcpf(cnt + 1.0f); /* off-chain: used next step */         \
    emptyBits = own ? 0u : emptyBits;                                                \
    pk |= (unsigned long long)(unsigned)(cid + 1) << ((J) * 8);                      \
  } while (0)

__global__ __launch_bounds__(64, 1) void k_cluster(const float* __restrict__ embC,
                                                   const int* __restrict__ nvalid,
                                                   unsigned char* __restrict__ cidArr,
                                                   int cap) {
  const int b = blockIdx.x;
  const int lane = threadIdx.x;
  const int cl = lane & 31;
  const int n = nvalid[b];
  if (n <= 0) return;

  const float* src = embC + (size_t)b * cap * 8;  // uniform -> SGPR pair
  unsigned char* cidB = cidArr + (size_t)b * HW_;

  float C0 = 0.f, C1 = 0.f, C2 = 0.f, C3 = 0.f, C4 = 0.f, C5 = 0.f, C6 = 0.f, C7 = 0.f;
  float cnt = 0.f, inv = 1.0f;
  unsigned emptyBits = 0x7F800000u;
  int nact = 0;
  unsigned long long pk = 0ULL;

  u32x16 a0, b0, a1, b1;  // 2 slots x 2 loads = 64 SGPRs
  // prologue: group0 -> slot0 (wait), group1 -> slot1 (in flight)
  SLOAD(a0, b0, 0u);
  SWAIT(a0, b0);
  SLOAD(a1, b1, 128u);
  unsigned offNext = 256u;

  const int nOct = (n + 7) >> 3;  // 8 pixels (2 groups) per iteration
  for (int o = 0; o < nOct; ++o) {
    STEPS(0, a0, 0); STEPS(1, a0, 8); STEPS(2, b0, 0); STEPS(3, b0, 8);
    SWAIT(a1, b1);               // group(2o+1) arrived (only one outstanding)
    SLOAD(a0, b0, offNext);      // issue group(2o+2) into just-consumed slot0
    offNext += 128u;
    STEPS(4, a1, 0); STEPS(5, a1, 8); STEPS(6, b1, 0); STEPS(7, b1, 8);
    if (lane == 0) *(unsigned long long*)(cidB + o * 8) = pk;
    pk = 0ULL;
    SWAIT(a0, b0);               // group(2o+2) arrived
    SLOAD(a1, b1, offNext);      // issue group(2o+3) into slot1
    offNext += 128u;
  }
}

// ---------------- scatter cid bytes to the per-pixel lane map ----------------
__global__ void k_scatter(const unsigned char* __restrict__ cidArr,
                          const int* __restrict__ idxC, const int* __restrict__ nvalid,
                          unsigned char* __restrict__ lanes, int cap) {
  const int b = blockIdx.y;
  const int n = nvalid[b];
  for (int j = blockIdx.x * blockDim.x + threadIdx.x; j < n; j += gridDim.x * blockDim.x) {
    lanes[(size_t)b * HW_ + idxC[(size_t)b * cap + j]] = cidArr[(size_t)b * HW_ + j];
  }
}

// ---------------- per-(b,h) segment sums over 33 lane bins ----------------
__global__ void k_rowsum(const unsigned char* __restrict__ lanes,
                         const float* __restrict__ offp, const float* __restrict__ zp,
                         float* __restrict__ cnt, float* __restrict__ sx,
                         float* __restrict__ sz) {
  const int bh = blockIdx.x;
  const int b = bh >> 9, h = bh & 511;
  __shared__ float sc[33], sxx[33], szz[33];
  const int t = threadIdx.x;
  if (t < 33) { sc[t] = 0.f; sxx[t] = 0.f; szz[t] = 0.f; }
  __syncthreads();
  const size_t base = (size_t)bh * W_;
  for (int x = t; x < W_; x += 256) {
    int ln = lanes[base + x];
    float o = offp[base + x];
    float sig = 1.0f / (1.0f + expf(-o));
    float xa = (float)x + sig;
    float zv = zp[base + x];
    atomicAdd(&sc[ln], 1.0f);
    atomicAdd(&sxx[ln], xa);
    atomicAdd(&szz[ln], zv);
  }
  __syncthreads();
  if (t >= 1 && t < 33) {
    size_t o = ((size_t)b * K_ + (t - 1)) * H_ + h;
    cnt[o] = sc[t]; sx[o] = sxx[t]; sz[o] = szz[t];
  }
}

// ---------------- validity + point assembly ----------------
__global__ void k_final(const float* __restrict__ cnt, const float* __restrict__ sx,
                        const float* __restrict__ sz, float* __restrict__ out) {
  const int bk = blockIdx.x;
  const int b = bk >> 5, k = bk & 31;
  const int h = threadIdx.x;
  const size_t o = (size_t)bk * H_ + h;
  float c = cnt[o];
  float sc_ = c, sn = (c > 0.f) ? 1.f : 0.f;
#pragma unroll
  for (int off = 32; off >= 1; off >>= 1) {
    sc_ += __shfl_down(sc_, off);
    sn += __shfl_down(sn, off);
  }
  __shared__ float rs[8], rn[8], tot[2];
  const int wid = h >> 6, lid = h & 63;
  if (lid == 0) { rs[wid] = sc_; rn[wid] = sn; }
  __syncthreads();
  if (h == 0) {
    float a = 0, bb = 0;
#pragma unroll
    for (int q = 0; q < 8; ++q) { a += rs[q]; bb += rn[q]; }
    tot[0] = a; tot[1] = bb;
  }
  __syncthreads();
  float size = tot[0], nrows = tot[1];
  bool valid = (c > 0.f) && (size >= 50.f) && (nrows >= 2.f);
  float mx = sx[o] / fmaxf(c, 1.f);
  float mz = sz[o] / fmaxf(c, 1.f);
  float xw = (512.0f - ((float)h + 0.5f)) * 0.2f;
  float yw = -(mx - 256.0f) * 0.2f;
  out[((size_t)(b * 3 + 0) * K_ + k) * H_ + h] = valid ? xw : 0.f;
  out[((size_t)(b * 3 + 1) * K_ + k) * H_ + h] = valid ? yw : 0.f;
  out[((size_t)(b * 3 + 2) * K_ + k) * H_ + h] = valid ? mz : 0.f;
  out[(size_t)B_ * 3 * K_ * H_ + (size_t)bk * H_ + h] = valid ? 1.f : 0.f;
}

extern "C" void kernel_launch(void* const* d_in, const int* in_sizes, int n_in,
                              void* d_out, int out_size, void* d_ws, size_t ws_size,
                              hipStream_t stream) {
  const float* seg  = (const float*)d_in[0];
  const float* emb  = (const float*)d_in[1];
  const float* offp = (const float*)d_in[2];
  const float* zp   = (const float*)d_in[3];
  float* out = (float*)d_out;
  char* ws = (char*)d_ws;

  const size_t lanesOff = 0;
  const size_t cntOff   = (size_t)B_ * HW_;
  const size_t sxOff    = cntOff + (size_t)B_ * K_ * H_ * 4;
  const size_t szOff    = sxOff  + (size_t)B_ * K_ * H_ * 4;
  const size_t nvOff    = szOff  + (size_t)B_ * K_ * H_ * 4;
  const size_t ccOff    = nvOff + 256;
  const size_t cbOff    = ccOff + 1024;
  const size_t cidOff   = cbOff + 1024;                      // u8 [B][HW_] = 2 MiB
  const size_t idxOff   = cidOff + (size_t)B_ * HW_;
  size_t avail = (ws_size > idxOff + 8192) ? (ws_size - idxOff - 8192) : 0;  // staging slack
  long long capLL = (long long)(avail / ((size_t)B_ * 36));  // 4B idx + 32B emb per entry
  if (capLL > (long long)HW_) capLL = HW_;
  if (capLL < 2) capLL = 2;
  capLL &= ~1LL;  // keep per-batch embC base 64B-aligned (s_load_dwordx16)
  const int cap = (int)capLL;
  const size_t embOff = idxOff + (size_t)B_ * cap * 4;

  unsigned char* lanes = (unsigned char*)(ws + lanesOff);
  float* cnt = (float*)(ws + cntOff);
  float* sx  = (float*)(ws + sxOff);
  float* sz  = (float*)(ws + szOff);
  int* nvalid = (int*)(ws + nvOff);
  int* chunkCnt  = (int*)(ws + ccOff);
  int* chunkBase = (int*)(ws + cbOff);
  unsigned char* cidArr = (unsigned char*)(ws + cidOff);
  int* idxC   = (int*)(ws + idxOff);
  float* embC = (float*)(ws + embOff);

  k_count<<<B_ * CH_, 256, 0, stream>>>(seg, chunkCnt);
  k_scan<<<1, 128, 0, stream>>>(chunkCnt, chunkBase, nvalid, cap);
  k_fill<<<B_ * CH_, 256, 0, stream>>>(seg, emb, chunkBase, lanes, idxC, embC, cap);
  k_cluster<<<B_, 64, 0, stream>>>(embC, nvalid, cidArr, cap);
  k_scatter<<<dim3(64, B_), 256, 0, stream>>>(cidArr, idxC, nvalid, lanes, cap);
  k_rowsum<<<B_ * H_, 256, 0, stream>>>(lanes, offp, zp, cnt, sx, sz);
  k_final<<<B_ * K_, H_, 0, stream>>>(cnt, sx, sz, out);
}

// Round 9
// 3524.983 us; speedup vs baseline: 1.7766x; 1.1265x over previous
//
#include <hip/hip_runtime.h>

#define HW_ (512 * 512)
#define B_ 8
#define H_ 512
#define W_ 512
#define K_ 32
#define CH_ 16
#define CHPIX_ (HW_ / CH_)  // 16384 pixels per chunk

// ---------------- compact phase A: per-chunk valid count ----------------
__global__ void k_count(const float* __restrict__ seg, int* __restrict__ chunkCnt) {
  const int blk = blockIdx.x;  // b*CH_ + c
  const int t = threadIdx.x;
  const float4* __restrict__ s4 = (const float4*)(seg + (size_t)blk * CHPIX_) + (size_t)t * 16;
  int cnt = 0;
#pragma unroll
  for (int j = 0; j < 16; ++j) {
    float4 v = s4[j];
    cnt += (v.x >= 0.9f) + (v.y >= 0.9f) + (v.z >= 0.9f) + (v.w >= 0.9f);
  }
  __shared__ int red[256];
  red[t] = cnt;
  __syncthreads();
  for (int off = 128; off > 0; off >>= 1) {
    if (t < off) red[t] += red[t + off];
    __syncthreads();
  }
  if (t == 0) chunkCnt[blk] = red[0];
}

// ---------------- compact phase B: per-batch chunk base offsets ----------------
__global__ void k_scan(const int* __restrict__ chunkCnt, int* __restrict__ chunkBase,
                       int* __restrict__ nvalid, int cap) {
  const int t = threadIdx.x;  // b*CH_ + c
  if (t < B_ * CH_) {
    const int b = t / CH_, c = t % CH_;
    int base = 0;
    for (int q = 0; q < c; ++q) base += chunkCnt[b * CH_ + q];
    chunkBase[t] = base;
    if (c == CH_ - 1) nvalid[b] = min(base + chunkCnt[t], cap);
  }
}

// ---------------- compact phase C: ordered compaction + gather + lanes memset ----------------
__global__ void k_fill(const float* __restrict__ seg, const float* __restrict__ emb,
                       const int* __restrict__ chunkBase, unsigned char* __restrict__ lanes,
                       int* __restrict__ idxC, float* __restrict__ embC, int cap) {
  const int blk = blockIdx.x;  // b*CH_ + c
  const int b = blk / CH_;
  const int t = threadIdx.x;
  const size_t pixbase = (size_t)blk * CHPIX_ + (size_t)t * 64;
  const float4* __restrict__ s4 = (const float4*)(seg + pixbase);

  int cnt = 0;
#pragma unroll
  for (int j = 0; j < 16; ++j) {
    float4 v = s4[j];
    cnt += (v.x >= 0.9f) + (v.y >= 0.9f) + (v.z >= 0.9f) + (v.w >= 0.9f);
  }
  __shared__ int pre[256];
  pre[t] = cnt;
  __syncthreads();
  for (int off = 1; off < 256; off <<= 1) {
    int mine = pre[t];
    int add = (t >= off) ? pre[t - off] : 0;
    __syncthreads();
    pre[t] = mine + add;
    __syncthreads();
  }
  int w = chunkBase[blk] + pre[t] - cnt;

  uint4 z = {0u, 0u, 0u, 0u};
  uint4* lz = (uint4*)(lanes + pixbase);
  lz[0] = z; lz[1] = z; lz[2] = z; lz[3] = z;

  const float* __restrict__ eb = emb + (size_t)b * 8 * HW_;
  const int pixInB = (int)(pixbase - (size_t)b * HW_);
  for (int j = 0; j < 16; ++j) {
    float4 v = s4[j];
    float sv[4] = {v.x, v.y, v.z, v.w};
#pragma unroll
    for (int q = 0; q < 4; ++q) {
      if (sv[q] >= 0.9f && w < cap) {
        const int p = pixInB + j * 4 + q;
        idxC[(size_t)b * cap + w] = p;
        float* dst = embC + ((size_t)b * cap + w) * 8;
#pragma unroll
        for (int dd = 0; dd < 8; ++dd) dst[dd] = eb[(size_t)dd * HW_ + p];
        ++w;
      }
    }
  }
}

// ---------------- sequential clustering: speculative-dsq pipeline ----------------
// 8 blocks x 1 wave, one batch each. Centers on lanes 0-31 (32-63 mirror).
// Per step, the ON-CHAIN work is only: dsq_j = fma(w_prev, fma(w_prev, dsq_prev,
// -2g), dspec) -> key -> 4x DPP min -> readlane/s_min -> decide -> w.
// All heavy work (C update, t correction, next tspec + |tspec|^2 tree, g dot,
// e broadcast) depends only on w_prev and runs OFF-chain, filling stall slots.
// Identity: C_{j+1} = C_j + w*t_j, so |e_{j+1}-C_{j+1}|^2
//         = |tspec|^2 - 2w*(t_j . tspec) + w^2*|t_j|^2   (exact algebra).
// Tile = 64 pixels (2KB/phase), staged with 2x global_load_lds; td/td2 hold the
// tile in registers; next tile's regs prefetched mid-tile under vmcnt(0).

#define TILE_ 64

__device__ __forceinline__ void stage16(const float* g, float* l) {
  __builtin_amdgcn_global_load_lds(
      (const __attribute__((address_space(1))) void*)g,
      (__attribute__((address_space(3))) void*)l, 16, 0, 0);
}

#define RLF(V, L) __uint_as_float((unsigned)__builtin_amdgcn_readlane(__float_as_int(V), (L)))
#define RLU(V, L) ((unsigned)__builtin_amdgcn_readlane((int)(V), (L)))
#define DPPMIN(CTRL)                                                                  \
  {                                                                                   \
    unsigned mr_ = (unsigned)__builtin_amdgcn_update_dpp(0, (int)mn, CTRL, 0xF, 0xF, true); \
    mn = mn < mr_ ? mn : mr_;                                                         \
  }

// PK: pack register; SH: byte slot 0..7; TD: float4 holding pixel (j+1)'s halves;
// L: lane of the low half (even); pixel j+1's 8 floats at lanes L (x,y,z,w), L+1.
#define STEPX(PK, SH, TD, L)                                                     \
  do {                                                                           \
    /* on-chain: corrected dsq for pixel j */                                    \
    float dsq = __builtin_fmaf(wp, __builtin_fmaf(wp, dsqq, m2g), dspec);        \
    unsigned db = __float_as_uint(dsq);                                          \
    unsigned dbm = db > emptyBits ? db : emptyBits; /* empty center -> inf */    \
    unsigned mn = (dbm & 0xFFFFFFE0u) | (unsigned)cl;                            \
    DPPMIN(0xB1) DPPMIN(0x4E) DPPMIN(0x141) DPPMIN(0x140)                        \
    unsigned q0 = RLU(mn, 0), q1 = RLU(mn, 16);                                  \
    unsigned mv = q0 < q1 ? q0 : q1; /* uniform -> SALU */                       \
    bool join = mv < 0x41100000u;    /* dsq < 9.0 <=> sqrt(dsq) < 3 */           \
    int cid = join ? (int)(mv & 31u) : (nact < 31 ? nact : 31);                  \
    nact += join ? 0 : 1;                                                        \
    bool own = (cl == cid);                                                      \
    float wj = join ? inv : 1.0f;                                                \
    float w = own ? wj : 0.0f;                                                   \
    /* off-chain: apply PREVIOUS pixel's update, then correct t_j */             \
    C0 = __builtin_fmaf(wp, t0, C0); C1 = __builtin_fmaf(wp, t1, C1);            \
    C2 = __builtin_fmaf(wp, t2, C2); C3 = __builtin_fmaf(wp, t3, C3);            \
    C4 = __builtin_fmaf(wp, t4, C4); C5 = __builtin_fmaf(wp, t5, C5);            \
    C6 = __builtin_fmaf(wp, t6, C6); C7 = __builtin_fmaf(wp, t7, C7);            \
    t0 = __builtin_fmaf(-wp, t0, s0); t1 = __builtin_fmaf(-wp, t1, s1);          \
    t2 = __builtin_fmaf(-wp, t2, s2); t3 = __builtin_fmaf(-wp, t3, s3);          \
    t4 = __builtin_fmaf(-wp, t4, s4); t5 = __builtin_fmaf(-wp, t5, s5);          \
    t6 = __builtin_fmaf(-wp, t6, s6); t7 = __builtin_fmaf(-wp, t7, s7);          \
    /* e_{j+1} broadcast and speculative tspec / |tspec|^2 / g */                \
    const float e0n = RLF((TD).x, (L)), e1n = RLF((TD).y, (L));                  \
    const float e2n = RLF((TD).z, (L)), e3n = RLF((TD).w, (L));                  \
    const float e4n = RLF((TD).x, (L) + 1), e5n = RLF((TD).y, (L) + 1);          \
    const float e6n = RLF((TD).z, (L) + 1), e7n = RLF((TD).w, (L) + 1);          \
    s0 = e0n - C0; s1 = e1n - C1; s2 = e2n - C2; s3 = e3n - C3;                  \
    s4 = e4n - C4; s5 = e5n - C5; s6 = e6n - C6; s7 = e7n - C7;                  \
    float p0 = s0 * s0; p0 = __builtin_fmaf(s1, s1, p0);                         \
    float p1 = s2 * s2; p1 = __builtin_fmaf(s3, s3, p1);                         \
    float p2 = s4 * s4; p2 = __builtin_fmaf(s5, s5, p2);                         \
    float p3 = s6 * s6; p3 = __builtin_fmaf(s7, s7, p3);                         \
    dspec = (p0 + p1) + (p2 + p3);                                               \
    float gg = t0 * s0; gg = __builtin_fmaf(t1, s1, gg);                         \
    gg = __builtin_fmaf(t2, s2, gg); gg = __builtin_fmaf(t3, s3, gg);            \
    gg = __builtin_fmaf(t4, s4, gg); gg = __builtin_fmaf(t5, s5, gg);            \
    gg = __builtin_fmaf(t6, s6, gg); gg = __builtin_fmaf(t7, s7, gg);            \
    m2g = -2.0f * gg;                                                            \
    dsqq = dsq;                                                                  \
    wp = w;                                                                      \
    cnt += own ? 1.0f : 0.0f;                                                    \
    inv = __builtin_amdgcn_rcpf(cnt + 1.0f); /* used next step */                \
    emptyBits = own ? 0u : emptyBits;                                            \
    PK |= (unsigned long long)(unsigned)(cid + 1) << ((SH) * 8);                 \
  } while (0)

__global__ __launch_bounds__(64, 1) void k_cluster(const float* __restrict__ embC,
                                                   const int* __restrict__ nvalid,
                                                   unsigned char* __restrict__ cidArr,
                                                   int cap) {
  __shared__ float lds[1024];  // 2 phases x 512 floats (2KB per phase)
  const int b = blockIdx.x;
  const int lane = threadIdx.x;
  const int cl = lane & 31;
  const int n = nvalid[b];
  if (n <= 0) return;
  const int nTiles = (n + TILE_ - 1) / TILE_;

  const float* src = embC + (size_t)b * cap * 8 + lane * 4;
  unsigned char* cidB = cidArr + (size_t)b * HW_;
  const float4* f4 = (const float4*)lds;

  float C0 = 0.f, C1 = 0.f, C2 = 0.f, C3 = 0.f, C4 = 0.f, C5 = 0.f, C6 = 0.f, C7 = 0.f;
  float t0 = 0.f, t1 = 0.f, t2 = 0.f, t3 = 0.f, t4 = 0.f, t5 = 0.f, t6 = 0.f, t7 = 0.f;
  float s0, s1, s2, s3, s4, s5, s6, s7;
  float cnt = 0.f, inv = 1.0f, wp = 0.f, m2g = 0.f, dsqq = 0.f, dspec;
  unsigned emptyBits = 0x7F800000u;
  int nact = 0;
  unsigned long long pk0 = 0, pk1 = 0, pk2 = 0, pk3 = 0, pk4 = 0, pk5 = 0, pk6 = 0, pk7 = 0;

  // prologue: stage tile 0 (2KB), wait, pull my 2x16B into registers
  stage16(src, lds);
  stage16(src + 256, lds + 256);
  asm volatile("s_waitcnt vmcnt(0)" ::: "memory");
  __builtin_amdgcn_sched_barrier(0);
  float4 td = f4[lane], td2 = f4[64 + lane];
  float4 tdN = td, td2N = td2;

  // pipeline init: tspec for pixel 0 against C=0 (s = e_0), dspec = |e_0|^2
  s0 = RLF(td.x, 0); s1 = RLF(td.y, 0); s2 = RLF(td.z, 0); s3 = RLF(td.w, 0);
  s4 = RLF(td.x, 1); s5 = RLF(td.y, 1); s6 = RLF(td.z, 1); s7 = RLF(td.w, 1);
  {
    float p0 = s0 * s0 + s1 * s1, p1 = s2 * s2 + s3 * s3;
    float p2 = s4 * s4 + s5 * s5, p3 = s6 * s6 + s7 * s7;
    dspec = (p0 + p1) + (p2 + p3);
  }

  for (int ti = 0; ti < nTiles; ++ti) {
    const bool more = (ti + 1 < nTiles);
    if (more) {  // stage next tile into the other phase
      stage16(src + (size_t)(ti + 1) * 512, lds + ((ti + 1) & 1) * 512);
      stage16(src + (size_t)(ti + 1) * 512 + 256, lds + ((ti + 1) & 1) * 512 + 256);
    }
    // steps 0..47: e_{j+1} from pixels 1..48 of this tile
    STEPX(pk0, 0, td, 2);   STEPX(pk0, 1, td, 4);   STEPX(pk0, 2, td, 6);   STEPX(pk0, 3, td, 8);
    STEPX(pk0, 4, td, 10);  STEPX(pk0, 5, td, 12);  STEPX(pk0, 6, td, 14);  STEPX(pk0, 7, td, 16);
    STEPX(pk1, 0, td, 18);  STEPX(pk1, 1, td, 20);  STEPX(pk1, 2, td, 22);  STEPX(pk1, 3, td, 24);
    STEPX(pk1, 4, td, 26);  STEPX(pk1, 5, td, 28);  STEPX(pk1, 6, td, 30);  STEPX(pk1, 7, td, 32);
    STEPX(pk2, 0, td, 34);  STEPX(pk2, 1, td, 36);  STEPX(pk2, 2, td, 38);  STEPX(pk2, 3, td, 40);
    STEPX(pk2, 4, td, 42);  STEPX(pk2, 5, td, 44);  STEPX(pk2, 6, td, 46);  STEPX(pk2, 7, td, 48);
    STEPX(pk3, 0, td, 50);  STEPX(pk3, 1, td, 52);  STEPX(pk3, 2, td, 54);  STEPX(pk3, 3, td, 56);
    STEPX(pk3, 4, td, 58);  STEPX(pk3, 5, td, 60);  STEPX(pk3, 6, td, 62);  STEPX(pk4, 0, td2, 0);
    STEPX(pk4, 1, td2, 2);  STEPX(pk4, 2, td2, 4);  STEPX(pk4, 3, td2, 6);  STEPX(pk4, 4, td2, 8);
    STEPX(pk4, 5, td2, 10); STEPX(pk4, 6, td2, 12); STEPX(pk4, 7, td2, 14); STEPX(pk5, 0, td2, 16);
    STEPX(pk5, 1, td2, 18); STEPX(pk5, 2, td2, 20); STEPX(pk5, 3, td2, 22); STEPX(pk5, 4, td2, 24);
    STEPX(pk5, 5, td2, 26); STEPX(pk5, 6, td2, 28); STEPX(pk5, 7, td2, 30); STEPX(pk6, 0, td2, 32);

    if (more) {
      // stages for ti+1 issued 48 steps ago -> retired; no newer VMEM ops.
      asm volatile("s_waitcnt vmcnt(0)" ::: "memory");
      __builtin_amdgcn_sched_barrier(0);
      const int ph = ((ti + 1) & 1) * 128;
      tdN = f4[ph + lane];
      td2N = f4[ph + 64 + lane];
    }
    // steps 48..62: e from pixels 49..63; step 63: e = pixel 0 of NEXT tile
    STEPX(pk6, 1, td2, 34); STEPX(pk6, 2, td2, 36); STEPX(pk6, 3, td2, 38); STEPX(pk6, 4, td2, 40);
    STEPX(pk6, 5, td2, 42); STEPX(pk6, 6, td2, 44); STEPX(pk6, 7, td2, 46); STEPX(pk7, 0, td2, 48);
    STEPX(pk7, 1, td2, 50); STEPX(pk7, 2, td2, 52); STEPX(pk7, 3, td2, 54); STEPX(pk7, 4, td2, 56);
    STEPX(pk7, 5, td2, 58); STEPX(pk7, 6, td2, 60); STEPX(pk7, 7, td2, 62); STEPX(pk0, 0, tdN, 0);
    // NOTE: the last STEPX above decided pixel 63 and (re)wrote pk0 slot 0 --
    // pk0 slot 0 belongs to NEXT tile's pixel 0?? No: it belongs to THIS tile's
    // pixel 63? -- pixel index = step index: steps ran 0..63, packing order
    // pk0[0..7]=px0..7 ... pk7[0..7]=px56..63. The final call must pack pk7
    // slot 7. Fixed mapping below.
    (void)0;

    if (lane == 0) {
      unsigned char* cptr = cidB + ti * TILE_;
      uint4 v;
      v.x = (unsigned)pk0; v.y = (unsigned)(pk0 >> 32);
      v.z = (unsigned)pk1; v.w = (unsigned)(pk1 >> 32);
      *(uint4*)(cptr + 0) = v;
      v.x = (unsigned)pk2; v.y = (unsigned)(pk2 >> 32);
      v.z = (unsigned)pk3; v.w = (unsigned)(pk3 >> 32);
      *(uint4*)(cptr + 16) = v;
      v.x = (unsigned)pk4; v.y = (unsigned)(pk4 >> 32);
      v.z = (unsigned)pk5; v.w = (unsigned)(pk5 >> 32);
      *(uint4*)(cptr + 32) = v;
      v.x = (unsigned)pk6; v.y = (unsigned)(pk6 >> 32);
      v.z = (unsigned)pk7; v.w = (unsigned)(pk7 >> 32);
      *(uint4*)(cptr + 48) = v;
    }
    pk0 = pk1 = pk2 = pk3 = pk4 = pk5 = pk6 = pk7 = 0ULL;
    td = tdN;
    td2 = td2N;
  }
}
// Correct the step->pk mapping: the 64 STEPX calls above pack, in order,
// pk0 x8, pk1 x8, pk2 x8, pk3 x7, pk4 x1(slot0)... The sequence as written is:
// 31 steps into pk0..pk3(slot6), then STEPX(pk4,0,...) is step 31 (pixel 31),
// continuing contiguously so that step s packs pk[s>>3] slot (s&7):
// steps 0..7 -> pk0, 8..15 -> pk1, 16..23 -> pk2, 24..30 -> pk3 slots 0..6,
// step 31 -> pk4 slot 0? That would misalign. The call list was constructed
// so that the (PK, SH) pairs advance exactly as (s>>3, s&7) for s = 0..63:
// verify: call #32 is STEPX(pk4,0) => s=31 gets pk3 slot7? NO.
// To avoid any ambiguity the list above uses (pk3,6) at s=30, (pk4,0) at s=31.
// That is WRONG by one slot. The corrected full sequence is generated below
// as a second definition used by the kernel; the kernel above is not compiled.

// ---------------- scatter cid bytes to the per-pixel lane map ----------------
__global__ void k_scatter(const unsigned char* __restrict__ cidArr,
                          const int* __restrict__ idxC, const int* __restrict__ nvalid,
                          unsigned char* __restrict__ lanes, int cap) {
  const int b = blockIdx.y;
  const int n = nvalid[b];
  for (int j = blockIdx.x * blockDim.x + threadIdx.x; j < n; j += gridDim.x * blockDim.x) {
    lanes[(size_t)b * HW_ + idxC[(size_t)b * cap + j]] = cidArr[(size_t)b * HW_ + j];
  }
}

// ---------------- per-(b,h) segment sums over 33 lane bins ----------------
__global__ void k_rowsum(const unsigned char* __restrict__ lanes,
                         const float* __restrict__ offp, const float* __restrict__ zp,
                         float* __restrict__ cnt, float* __restrict__ sx,
                         float* __restrict__ sz) {
  const int bh = blockIdx.x;
  const int b = bh >> 9, h = bh & 511;
  __shared__ float sc[33], sxx[33], szz[33];
  const int t = threadIdx.x;
  if (t < 33) { sc[t] = 0.f; sxx[t] = 0.f; szz[t] = 0.f; }
  __syncthreads();
  const size_t base = (size_t)bh * W_;
  for (int x = t; x < W_; x += 256) {
    int ln = lanes[base + x];
    float o = offp[base + x];
    float sig = 1.0f / (1.0f + expf(-o));
    float xa = (float)x + sig;
    float zv = zp[base + x];
    atomicAdd(&sc[ln], 1.0f);
    atomicAdd(&sxx[ln], xa);
    atomicAdd(&szz[ln], zv);
  }
  __syncthreads();
  if (t >= 1 && t < 33) {
    size_t o = ((size_t)b * K_ + (t - 1)) * H_ + h;
    cnt[o] = sc[t]; sx[o] = sxx[t]; sz[o] = szz[t];
  }
}

// ---------------- validity + point assembly ----------------
__global__ void k_final(const float* __restrict__ cnt, const float* __restrict__ sx,
                        const float* __restrict__ sz, float* __restrict__ out) {
  const int bk = blockIdx.x;
  const int b = bk >> 5, k = bk & 31;
  const int h = threadIdx.x;
  const size_t o = (size_t)bk * H_ + h;
  float c = cnt[o];
  float sc_ = c, sn = (c > 0.f) ? 1.f : 0.f;
#pragma unroll
  for (int off = 32; off >= 1; off >>= 1) {
    sc_ += __shfl_down(sc_, off);
    sn += __shfl_down(sn, off);
  }
  __shared__ float rs[8], rn[8], tot[2];
  const int wid = h >> 6, lid = h & 63;
  if (lid == 0) { rs[wid] = sc_; rn[wid] = sn; }
  __syncthreads();
  if (h == 0) {
    float a = 0, bb = 0;
#pragma unroll
    for (int q = 0; q < 8; ++q) { a += rs[q]; bb += rn[q]; }
    tot[0] = a; tot[1] = bb;
  }
  __syncthreads();
  float size = tot[0], nrows = tot[1];
  bool valid = (c > 0.f) && (size >= 50.f) && (nrows >= 2.f);
  float mx = sx[o] / fmaxf(c, 1.f);
  float mz = sz[o] / fmaxf(c, 1.f);
  float xw = (512.0f - ((float)h + 0.5f)) * 0.2f;
  float yw = -(mx - 256.0f) * 0.2f;
  out[((size_t)(b * 3 + 0) * K_ + k) * H_ + h] = valid ? xw : 0.f;
  out[((size_t)(b * 3 + 1) * K_ + k) * H_ + h] = valid ? yw : 0.f;
  out[((size_t)(b * 3 + 2) * K_ + k) * H_ + h] = valid ? mz : 0.f;
  out[(size_t)B_ * 3 * K_ * H_ + (size_t)bk * H_ + h] = valid ? 1.f : 0.f;
}

// ---------------- k_cluster2: corrected (PK,SH) <-> step mapping ----------------
__global__ __launch_bounds__(64, 1) void k_cluster2(const float* __restrict__ embC,
                                                    const int* __restrict__ nvalid,
                                                    unsigned char* __restrict__ cidArr,
                                                    int cap) {
  __shared__ float lds[1024];
  const int b = blockIdx.x;
  const int lane = threadIdx.x;
  const int cl = lane & 31;
  const int n = nvalid[b];
  if (n <= 0) return;
  const int nTiles = (n + TILE_ - 1) / TILE_;

  const float* src = embC + (size_t)b * cap * 8 + lane * 4;
  unsigned char* cidB = cidArr + (size_t)b * HW_;
  const float4* f4 = (const float4*)lds;

  float C0 = 0.f, C1 = 0.f, C2 = 0.f, C3 = 0.f, C4 = 0.f, C5 = 0.f, C6 = 0.f, C7 = 0.f;
  float t0 = 0.f, t1 = 0.f, t2 = 0.f, t3 = 0.f, t4 = 0.f, t5 = 0.f, t6 = 0.f, t7 = 0.f;
  float s0, s1, s2, s3, s4, s5, s6, s7;
  float cnt = 0.f, inv = 1.0f, wp = 0.f, m2g = 0.f, dsqq = 0.f, dspec;
  unsigned emptyBits = 0x7F800000u;
  int nact = 0;
  unsigned long long pk0 = 0, pk1 = 0, pk2 = 0, pk3 = 0, pk4 = 0, pk5 = 0, pk6 = 0, pk7 = 0;

  stage16(src, lds);
  stage16(src + 256, lds + 256);
  asm volatile("s_waitcnt vmcnt(0)" ::: "memory");
  __builtin_amdgcn_sched_barrier(0);
  float4 td = f4[lane], td2 = f4[64 + lane];
  float4 tdN = td, td2N = td2;

  s0 = RLF(td.x, 0); s1 = RLF(td.y, 0); s2 = RLF(td.z, 0); s3 = RLF(td.w, 0);
  s4 = RLF(td.x, 1); s5 = RLF(td.y, 1); s6 = RLF(td.z, 1); s7 = RLF(td.w, 1);
  {
    float p0 = s0 * s0 + s1 * s1, p1 = s2 * s2 + s3 * s3;
    float p2 = s4 * s4 + s5 * s5, p3 = s6 * s6 + s7 * s7;
    dspec = (p0 + p1) + (p2 + p3);
  }

  // step s (pixel s of tile): pack -> pk[s>>3] slot (s&7); e source = pixel s+1:
  // p = s+1: p in 1..31 -> td lane 2p; p == 32..63 -> td2 lane 2(p-32); p == 64 -> tdN lane 0.
#define ROW8(PK, S0, TDa, La, TDb, Lb, TDc, Lc, TDd, Ld, TDe, Le, TDf, Lf, TDg, Lg, TDh, Lh) \
  STEPX(PK, 0, TDa, La); STEPX(PK, 1, TDb, Lb); STEPX(PK, 2, TDc, Lc); STEPX(PK, 3, TDd, Ld); \
  STEPX(PK, 4, TDe, Le); STEPX(PK, 5, TDf, Lf); STEPX(PK, 6, TDg, Lg); STEPX(PK, 7, TDh, Lh);

  for (int ti = 0; ti < nTiles; ++ti) {
    const bool more = (ti + 1 < nTiles);
    if (more) {
      stage16(src + (size_t)(ti + 1) * 512, lds + ((ti + 1) & 1) * 512);
      stage16(src + (size_t)(ti + 1) * 512 + 256, lds + ((ti + 1) & 1) * 512 + 256);
    }
    // steps 0..7   (e: px 1..8)
    ROW8(pk0, 0, td, 2, td, 4, td, 6, td, 8, td, 10, td, 12, td, 14, td, 16)
    // steps 8..15  (e: px 9..16)
    ROW8(pk1, 8, td, 18, td, 20, td, 22, td, 24, td, 26, td, 28, td, 30, td, 32)
    // steps 16..23 (e: px 17..24)
    ROW8(pk2, 16, td, 34, td, 36, td, 38, td, 40, td, 42, td, 44, td, 46, td, 48)
    // steps 24..31 (e: px 25..32; px32 -> td2 lane 0)
    ROW8(pk3, 24, td, 50, td, 52, td, 54, td, 56, td, 58, td, 60, td, 62, td2, 0)
    // steps 32..39 (e: px 33..40)
    ROW8(pk4, 32, td2, 2, td2, 4, td2, 6, td2, 8, td2, 10, td2, 12, td2, 14, td2, 16)
    // steps 40..47 (e: px 41..48)
    ROW8(pk5, 40, td2, 18, td2, 20, td2, 22, td2, 24, td2, 26, td2, 28, td2, 30, td2, 32)

    if (more) {
      asm volatile("s_waitcnt vmcnt(0)" ::: "memory");
      __builtin_amdgcn_sched_barrier(0);
      const int ph = ((ti + 1) & 1) * 128;
      tdN = f4[ph + lane];
      td2N = f4[ph + 64 + lane];
    }
    // steps 48..55 (e: px 49..56)
    ROW8(pk6, 48, td2, 34, td2, 36, td2, 38, td2, 40, td2, 42, td2, 44, td2, 46, td2, 48)
    // steps 56..63 (e: px 57..63, then px 0 of next tile)
    ROW8(pk7, 56, td2, 50, td2, 52, td2, 54, td2, 56, td2, 58, td2, 60, td2, 62, tdN, 0)

    if (lane == 0) {
      unsigned char* cptr = cidB + ti * TILE_;
      uint4 v;
      v.x = (unsigned)pk0; v.y = (unsigned)(pk0 >> 32);
      v.z = (unsigned)pk1; v.w = (unsigned)(pk1 >> 32);
      *(uint4*)(cptr + 0) = v;
      v.x = (unsigned)pk2; v.y = (unsigned)(pk2 >> 32);
      v.z = (unsigned)pk3; v.w = (unsigned)(pk3 >> 32);
      *(uint4*)(cptr + 16) = v;
      v.x = (unsigned)pk4; v.y = (unsigned)(pk4 >> 32);
      v.z = (unsigned)pk5; v.w = (unsigned)(pk5 >> 32);
      *(uint4*)(cptr + 32) = v;
      v.x = (unsigned)pk6; v.y = (unsigned)(pk6 >> 32);
      v.z = (unsigned)pk7; v.w = (unsigned)(pk7 >> 32);
      *(uint4*)(cptr + 48) = v;
    }
    pk0 = pk1 = pk2 = pk3 = pk4 = pk5 = pk6 = pk7 = 0ULL;
    td = tdN;
    td2 = td2N;
  }
#undef ROW8
}

extern "C" void kernel_launch(void* const* d_in, const int* in_sizes, int n_in,
                              void* d_out, int out_size, void* d_ws, size_t ws_size,
                              hipStream_t stream) {
  const float* seg  = (const float*)d_in[0];
  const float* emb  = (const float*)d_in[1];
  const float* offp = (const float*)d_in[2];
  const float* zp   = (const float*)d_in[3];
  float* out = (float*)d_out;
  char* ws = (char*)d_ws;

  const size_t lanesOff = 0;
  const size_t cntOff   = (size_t)B_ * HW_;
  const size_t sxOff    = cntOff + (size_t)B_ * K_ * H_ * 4;
  const size_t szOff    = sxOff  + (size_t)B_ * K_ * H_ * 4;
  const size_t nvOff    = szOff  + (size_t)B_ * K_ * H_ * 4;
  const size_t ccOff    = nvOff + 256;
  const size_t cbOff    = ccOff + 1024;
  const size_t cidOff   = cbOff + 1024;                      // u8 [B][HW_] = 2 MiB
  const size_t idxOff   = cidOff + (size_t)B_ * HW_;
  size_t avail = (ws_size > idxOff + 16384) ? (ws_size - idxOff - 16384) : 0;  // staging slack
  long long capLL = (long long)(avail / ((size_t)B_ * 36));  // 4B idx + 32B emb per entry
  if (capLL > (long long)HW_) capLL = HW_;
  if (capLL < 2) capLL = 2;
  capLL &= ~1LL;  // keep per-batch embC base 64B-aligned
  const int cap = (int)capLL;
  const size_t embOff = idxOff + (size_t)B_ * cap * 4;

  unsigned char* lanes = (unsigned char*)(ws + lanesOff);
  float* cnt = (float*)(ws + cntOff);
  float* sx  = (float*)(ws + sxOff);
  float* sz  = (float*)(ws + szOff);
  int* nvalid = (int*)(ws + nvOff);
  int* chunkCnt  = (int*)(ws + ccOff);
  int* chunkBase = (int*)(ws + cbOff);
  unsigned char* cidArr = (unsigned char*)(ws + cidOff);
  int* idxC   = (int*)(ws + idxOff);
  float* embC = (float*)(ws + embOff);

  k_count<<<B_ * CH_, 256, 0, stream>>>(seg, chunkCnt);
  k_scan<<<1, 128, 0, stream>>>(chunkCnt, chunkBase, nvalid, cap);
  k_fill<<<B_ * CH_, 256, 0, stream>>>(seg, emb, chunkBase, lanes, idxC, embC, cap);
  k_cluster2<<<B_, 64, 0, stream>>>(embC, nvalid, cidArr, cap);
  k_scatter<<<dim3(64, B_), 256, 0, stream>>>(cidArr, idxC, nvalid, lanes, cap);
  k_rowsum<<<B_ * H_, 256, 0, stream>>>(lanes, offp, zp, cnt, sx, sz);
  k_final<<<B_ * K_, H_, 0, stream>>>(cnt, sx, sz, out);
}